// Round 1
// 66.195 us; speedup vs baseline: 1.0299x; 1.0299x over previous
//
#include <hip/hip_runtime.h>
#include <cmath>

#define SITE 8
#define DIM 16
#define BATCH 8192

// d_ws layout (floats), padded M: matrix r at r*272, row k at k*17 (16 used + 1 pad)
//   [0 .. 7616)      M table: 28 matrices, entry r*272 + k*17 + j
//   [7616 .. 7648)   head vectors hv[2][16]
#define WS_MPAD 272
#define WS_KPAD 17
#define WS_MEND 7616
#define WS_HV   7616

__device__ __forceinline__ float fast_tanh(float a) {
    // 1 - 2/(exp(2a)+1): exact limits at +-inf, ~1e-7 rel error, one v_exp_f32.
    float t = __expf(2.0f * a);
    return 1.0f - 2.0f / (t + 1.0f);
}

// Kernel A: build the 28 pattern-independent 16x16 matrices + 2 head vectors.
// 29 blocks: blocks 0..27 build one matrix each (256 threads, each float4 task
// split 4-way over the i-dot, shuffle-reduced) -> 4 loads/thread instead of 16,
// 28 CUs busy instead of 7. Block 28: head vectors.
__global__ __launch_bounds__(256) void build_kernel(
    const float* __restrict__ embedding,  // (8,2,16)
    const float* __restrict__ head_w,     // (32,32)
    const float* __restrict__ body_w,     // (7,32,32,32)
    float* __restrict__ ws)
{
    const int tid = threadIdx.x;
    if (blockIdx.x < 28) {
        const int r    = blockIdx.x;      // matrix 0..27: r = s*4 + bit*2 + h
        const int task = tid >> 2;        // 0..63: one float4 of the matrix
        const int part = tid & 3;         // i-range [part*4, part*4+4)
        const int k    = task >> 2;
        const int j4   = task & 3;
        const int s    = r >> 2;
        const int bit  = (r >> 1) & 1;
        const int h    = r & 1;
        const int rowoff = (bit ^ h) << 4;    // +16 row block when bit^h
        const int ioff   = bit << 4;          // +16 middle block when bit
        const int coloff = (h << 4) + j4 * 4; // +16 col block when h
        const float sgn  = (bit && !h) ? -1.0f : 1.0f;
        const float* g3  = body_w + s * 32768 + (k + rowoff) * 1024 + ioff * 32 + coloff;
        const float* emb = embedding + (s + 1) * 32 + bit * 16;
        float ax = 0.f, ay = 0.f, az = 0.f, aw = 0.f;
        #pragma unroll
        for (int ii = 0; ii < 4; ++ii) {
            int i = part * 4 + ii;
            float e = emb[i];
            float4 g = *(const float4*)(g3 + i * 32);
            ax += e * g.x; ay += e * g.y; az += e * g.z; aw += e * g.w;
        }
        // sum the 4 parts (consecutive lanes): butterfly over lane bits 0,1
        ax += __shfl_xor(ax, 1); ay += __shfl_xor(ay, 1);
        az += __shfl_xor(az, 1); aw += __shfl_xor(aw, 1);
        ax += __shfl_xor(ax, 2); ay += __shfl_xor(ay, 2);
        az += __shfl_xor(az, 2); aw += __shfl_xor(aw, 2);
        if (part == 0) {
            float* dst = ws + r * WS_MPAD + k * WS_KPAD + j4 * 4;  // stride-17 rows
            dst[0] = sgn * ax; dst[1] = sgn * ay;
            dst[2] = sgn * az; dst[3] = sgn * aw;
        }
    } else {
        if (tid < 32) {
            int h = tid >> 4;
            int j = tid & 15;
            const float* emb = embedding + h * 16;   // site 0, row h
            float a = 0.f;
            if (h == 0) {
                #pragma unroll
                for (int k = 0; k < 16; ++k) a += emb[k] * head_w[k * 32 + j];
            } else {
                #pragma unroll
                for (int k = 0; k < 16; ++k) a += emb[k] * head_w[(k + 16) * 32 + (j + 16)];
            }
            ws[WS_HV + h * 16 + j] = fast_tanh(a);
        }
    }
}

// Kernel B: fused recurrence + scatter. 512 blocks x 512 threads; block handles
// 16 samples (one 32-lane wave-local group per sample, barrier-free recurrence).
// Halved block count -> halved redundant M-table staging (31 MB -> 15.5 MB L2).
__global__ __launch_bounds__(512) void recur_scatter_kernel(
    const int* __restrict__ data,     // (8192,8)
    const float* __restrict__ ws,
    float4* __restrict__ out4)        // (8192,16) float4
{
    __shared__ __align__(16) float Ml[WS_MEND];
    __shared__ __align__(16) float st[16][2][16];

    const int tid = threadIdx.x;

    // stage padded M table: 1904 float4 (pads carry garbage, never read)
    #pragma unroll
    for (int it = 0; it < 4; ++it) {
        int i4 = tid + 512 * it;
        if (i4 < WS_MEND / 4)
            ((float4*)Ml)[i4] = ((const float4*)ws)[i4];
    }

    const int pl = tid >> 5;              // group slot 0..15
    const int h  = (tid >> 4) & 1;
    const int j  = tid & 15;
    const int b  = blockIdx.x * 16 + pl;  // sample index

    // head value for this (h,j) — L2-hot global read, overlaps the LDS copy
    float hvv = ws[WS_HV + h * 16 + j];

    // pattern id from the sample's 8 bits
    const int4* d4 = (const int4*)(data + b * 8);
    int4 w0 = d4[0];
    int4 w1 = d4[1];
    int id = (w0.x & 1) | ((w0.y & 1) << 1) | ((w0.z & 1) << 2) | ((w0.w & 1) << 3)
           | ((w1.x & 1) << 4) | ((w1.y & 1) << 5) | ((w1.z & 1) << 6) | ((w1.w & 1) << 7);

    __syncthreads();

    // init: bit0==h -> hv[h], else 0
    float v = ((id & 1) == h) ? hvv : 0.f;
    st[pl][h][j] = v;                     // wave-local LDS, no barrier needed

    #pragma unroll
    for (int s = 1; s < SITE; ++s) {
        int bit = (id >> s) & 1;
        const float* src = st[pl][h ^ bit];
        const float* m   = Ml + ((s - 1) * 4 + bit * 2 + h) * WS_MPAD;
        float a0 = 0.f, a1 = 0.f, a2 = 0.f, a3 = 0.f;
        #pragma unroll
        for (int k = 0; k < 16; k += 4) {
            a0 += src[k]     * m[k * WS_KPAD + j];
            a1 += src[k + 1] * m[(k + 1) * WS_KPAD + j];
            a2 += src[k + 2] * m[(k + 2) * WS_KPAD + j];
            a3 += src[k + 3] * m[(k + 3) * WS_KPAD + j];
        }
        v = fast_tanh((a0 + a1) + (a2 + a3));
        st[pl][h][j] = v;                 // lockstep within wave
    }

    // write row b: 16 float4 = [e(4), zeros(8), o(4)]; lanes 0..15 of group
    if ((tid & 31) < 16) {
        int q = j;                        // 0..15
        float4 v4 = make_float4(0.f, 0.f, 0.f, 0.f);
        if (q < 4)        v4 = *(const float4*)&st[pl][0][q * 4];
        else if (q >= 12) v4 = *(const float4*)&st[pl][1][(q - 12) * 4];
        out4[b * 16 + q] = v4;
    }
}

extern "C" void kernel_launch(void* const* d_in, const int* in_sizes, int n_in,
                              void* d_out, int out_size, void* d_ws, size_t ws_size,
                              hipStream_t stream) {
    const int*   data      = (const int*)d_in[0];
    const float* embedding = (const float*)d_in[1];
    const float* head_w    = (const float*)d_in[2];
    const float* body_w    = (const float*)d_in[3];
    float* ws = (float*)d_ws;

    build_kernel<<<29, 256, 0, stream>>>(embedding, head_w, body_w, ws);
    recur_scatter_kernel<<<BATCH / 16, 512, 0, stream>>>(data, ws, (float4*)d_out);
}